// Round 24
// baseline (58.170 us; speedup 1.0000x reference)
//
#include <hip/hip_runtime.h>

// Problem sizes
#define NB  131072
#define ND1 40
#define ND2 10
#define NT0 120
#define NT1 5
#define NO0 3

#define NBW 16                  // batches per workgroup
#define XTILE (NBW * ND1 * ND2) // 6400 floats
#define PK  40                  // Ybf row pitch (bf16 elems)

typedef __attribute__((ext_vector_type(8))) short  short8;
typedef __attribute__((ext_vector_type(4))) float  f32x4;

// 2-wave (128-thread) blocks, 16 batches each; 8192 blocks.
// R22's phase-1 (load-all 12.5 float4/thread + cvt_pk) at half the block
// size: the phase barrier now couples only 2 waves (was 4), and 8
// independent blocks/CU (was 4) keep more decorrelated load streams in
// flight. R13's spill at this geometry is gone: w12/bias come from LDS,
// nt=1 halves st, cvt_pk cut temps -> peak live ~100 <= 128-reg cap
// ((128,2) law, R13-measured).
//  phase 1: wave w owns units [w*160,(w+1)*160): load-all -> fp32 FMA ->
//           v_cvt_pk_bf16_f32 -> Ybf[u][b][d] in LDS.
//  phase 2: wave w owns t-rows [w*64,(w+1)*64): 4 m-tiles, nt=1:
//           Z[t,b]=sum_d W11[t,d]*Y_u[d,b]; st += fc4[u]*relu(Z+bias1).
//  epilogue: out[o,b] = sum_t W12[o,t]*st[t,b] (2-wave LDS reduce).
__global__ __launch_bounds__(128, 2) void BL_36721970381090_kernel(
    const float* __restrict__ x,
    const float* __restrict__ W11,
    const float* __restrict__ fc2_w,
    const float* __restrict__ bias1,
    const float* __restrict__ W12,
    const float* __restrict__ fc4_w,
    const float* __restrict__ bias2,
    float* __restrict__ out)
{
    __shared__ __align__(16) unsigned short Ybf[NT1 * NBW * PK]; //  6400 B
    __shared__ float biasL[128 * NT1];                           //  2560 B
    __shared__ float w12L[NO0 * 128];                            //  1536 B
    __shared__ float b2L[4];
    __shared__ float redL[2 * NO0 * NBW];                        //   384 B

    const int tid = threadIdx.x;
    const int wg  = blockIdx.x;
    const int w   = tid >> 6;   // wave 0..1
    const int l   = tid & 63;
    const int lr  = l & 15;     // A row / B col within 16-tile
    const int lg  = l >> 4;     // k-group

    // ---------------- prologue: constants -> LDS --------------------------
    for (int i = tid; i < 128 * NT1; i += 128)
        biasL[i] = (i < NT0 * NT1) ? bias1[i] : 0.f;
    for (int i = tid; i < NO0 * 128; i += 128) {
        const int o = i >> 7, t = i & 127;
        w12L[i] = (t < NT0) ? W12[o * NT0 + t] : 0.f;
    }
    if (tid < NO0) b2L[tid] = bias2[tid];

    float fc4r[NT1];
#pragma unroll
    for (int u = 0; u < NT1; ++u) fc4r[u] = fc4_w[u];

    // A-fragments: W11 -> bf16, masked (t<120, d<40); wave w owns 64 t-rows
    short8 afr[4][2];
#pragma unroll
    for (int mt = 0; mt < 4; ++mt) {
        const int t  = w * 64 + mt * 16 + lr;
        const int tc = t < NT0 ? t : NT0 - 1;
#pragma unroll
        for (int kk = 0; kk < 2; ++kk) {
            const int cb = kk * 32 + lg * 8;
            const int cc = cb <= 32 ? cb : 0;
            const float4* pw = (const float4*)(W11 + tc * ND1 + cc);
            const float4 w0 = pw[0], w1 = pw[1];
            const bool v = (t < NT0) && (cb <= 32);
            unsigned p01, p23, p45, p67;
            asm("v_cvt_pk_bf16_f32 %0, %1, %2" : "=v"(p01) : "v"(w0.x), "v"(w0.y));
            asm("v_cvt_pk_bf16_f32 %0, %1, %2" : "=v"(p23) : "v"(w0.z), "v"(w0.w));
            asm("v_cvt_pk_bf16_f32 %0, %1, %2" : "=v"(p45) : "v"(w1.x), "v"(w1.y));
            asm("v_cvt_pk_bf16_f32 %0, %1, %2" : "=v"(p67) : "v"(w1.z), "v"(w1.w));
            short8 f;
            f[0] = v ? (short)(p01 & 0xFFFF) : (short)0;
            f[1] = v ? (short)(p01 >> 16)    : (short)0;
            f[2] = v ? (short)(p23 & 0xFFFF) : (short)0;
            f[3] = v ? (short)(p23 >> 16)    : (short)0;
            f[4] = v ? (short)(p45 & 0xFFFF) : (short)0;
            f[5] = v ? (short)(p45 >> 16)    : (short)0;
            f[6] = v ? (short)(p67 & 0xFFFF) : (short)0;
            f[7] = v ? (short)(p67 >> 16)    : (short)0;
            afr[mt][kk] = f;
        }
    }

    // ---------------- phase 1: load-all, then compute (wave-private) ------
    {
        const float* gx = x + (size_t)wg * XTILE;
        unsigned* Yw = (unsigned*)Ybf;
        const int  qbase = w * 160;          // wave-private unit range
        const bool act2  = (l < 32);

        float4 xq0[5], xq1[5], xq2[5];
        const float4* xr0 = (const float4*)(gx + (qbase + l) * 20);
        const float4* xr1 = (const float4*)(gx + (qbase + 64 + l) * 20);
        const float4* xr2 = (const float4*)(gx + (qbase + 128 + l) * 20);
#pragma unroll
        for (int i = 0; i < 5; ++i) xq0[i] = xr0[i];
#pragma unroll
        for (int i = 0; i < 5; ++i) xq1[i] = xr1[i];
        if (act2) {
#pragma unroll
            for (int i = 0; i < 5; ++i) xq2[i] = xr2[i];
        }

        const float4* bufs[3] = {xq0, xq1, xq2};
#pragma unroll
        for (int rep = 0; rep < 3; ++rep) {
            if (rep < 2 || act2) {
                const int q = qbase + rep * 64 + l;
                const int batch = q / 20;
                const int pair  = q - batch * 20;
                const float* xv = (const float*)bufs[rep];
#pragma unroll
                for (int u = 0; u < NT1; ++u) {
                    float a0 = 0.f, a1 = 0.f;
#pragma unroll
                    for (int s = 0; s < ND2; ++s) {
                        const float fw = fc2_w[u * ND2 + s];   // uniform: s_load
                        a0 = fmaf(xv[s], fw, a0);
                        a1 = fmaf(xv[10 + s], fw, a1);
                    }
                    unsigned pk;
                    asm("v_cvt_pk_bf16_f32 %0, %1, %2" : "=v"(pk) : "v"(a0), "v"(a1));
                    Yw[u * (NBW * PK / 2) + batch * (PK / 2) + pair] = pk;
                }
            }
        }
    }
    __syncthreads();   // Ybf + constants visible

    // ---------------- phase 2: MFMA + fused relu/fc4 (nt = 1) -------------
    float st[4][4];             // [m-tile][reg]
#pragma unroll
    for (int mt = 0; mt < 4; ++mt)
#pragma unroll
        for (int r = 0; r < 4; ++r) st[mt][r] = 0.f;

    const short8 zf = {0, 0, 0, 0, 0, 0, 0, 0};
#pragma unroll
    for (int u = 0; u < NT1; ++u) {
        float bv[4][4];
#pragma unroll
        for (int mt = 0; mt < 4; ++mt)
#pragma unroll
            for (int r = 0; r < 4; ++r)
                bv[mt][r] = biasL[(w * 64 + mt * 16 + lg * 4 + r) * NT1 + u];
        const unsigned short* Yu = &Ybf[u * (NBW * PK)];
        const short8 b0 = *(const short8*)&Yu[lr * PK + lg * 8];
        short8 b1 = zf;
        if (lg == 0) b1 = *(const short8*)&Yu[lr * PK + 32];
#pragma unroll
        for (int mt = 0; mt < 4; ++mt) {
            f32x4 z = {0.f, 0.f, 0.f, 0.f};
            z = __builtin_amdgcn_mfma_f32_16x16x32_bf16(afr[mt][0], b0, z, 0, 0, 0);
            z = __builtin_amdgcn_mfma_f32_16x16x32_bf16(afr[mt][1], b1, z, 0, 0, 0);
#pragma unroll
            for (int r = 0; r < 4; ++r)
                st[mt][r] += fc4r[u] * fmaxf(z[r] + bv[mt][r], 0.f);
        }
    }

    // ---------------- epilogue: out[o,b] = sum_t W12[o,t]*st --------------
    float po[NO0];
#pragma unroll
    for (int o = 0; o < NO0; ++o) {
        float a = 0.f;
#pragma unroll
        for (int mt = 0; mt < 4; ++mt)
#pragma unroll
            for (int r = 0; r < 4; ++r)
                a = fmaf(w12L[o * 128 + (w * 64 + mt * 16 + lg * 4 + r)],
                         st[mt][r], a);
        a += __shfl_xor(a, 16, 64);
        a += __shfl_xor(a, 32, 64);
        po[o] = a;
    }
    if (l < 16) {
#pragma unroll
        for (int o = 0; o < NO0; ++o)
            redL[(w * NO0 + o) * NBW + l] = po[o];
    }
    __syncthreads();

    if (tid < NO0 * NBW) {                    // 48 threads
        const int o  = tid >> 4;
        const int bc = tid & 15;
        const float s = redL[(0 * NO0 + o) * NBW + bc]
                      + redL[(1 * NO0 + o) * NBW + bc]
                      + b2L[o];
        out[((size_t)wg * NBW + bc) * NO0 + o] = s;
    }
}

extern "C" void kernel_launch(void* const* d_in, const int* in_sizes, int n_in,
                              void* d_out, int out_size, void* d_ws, size_t ws_size,
                              hipStream_t stream) {
    const float* x      = (const float*)d_in[0];
    const float* W11    = (const float*)d_in[1];
    const float* fc2_w  = (const float*)d_in[2];
    const float* bias1  = (const float*)d_in[3];
    const float* W12    = (const float*)d_in[4];
    const float* fc4_w  = (const float*)d_in[5];
    const float* bias2  = (const float*)d_in[6];
    float* out = (float*)d_out;

    const int blocks = NB / NBW;   // 8192
    BL_36721970381090_kernel<<<blocks, 128, 0, stream>>>(
        x, W11, fc2_w, bias1, W12, fc4_w, bias2, out);
}

// Round 25
// 56.172 us; speedup vs baseline: 1.0356x; 1.0356x over previous
//
#include <hip/hip_runtime.h>

// Problem sizes
#define NB  131072
#define ND1 40
#define ND2 10
#define NT0 120
#define NT1 5
#define NO0 3

typedef __attribute__((ext_vector_type(8))) short  short8;
typedef __attribute__((ext_vector_type(4))) float  f32x4;

// Zero-barrier wave-private kernel: each wave owns 16 batches end-to-end.
// Lane (lg=l>>4, lr=l&15) computes y for batch lr, d-chunk lg*8..lg*8+8 —
// exactly the MFMA B-frag layout (col=lane&15, k=(lane>>4)*8), so Y is
// built IN REGISTERS via v_cvt_pk_bf16_f32 (never touches LDS). Each wave
// computes all 128 t-rows (8 m-tiles) with A-frags from an XOR-swizzled
// LDS copy of W11 (swizzle byte^=(t&7)<<4 breaks the 128B-row 16-way bank
// conflict), reduces t in-lane + 2 shfls, stores out directly.
// ONE barrier total (prologue staging); afterwards 8192 waves run fully
// decorrelated -> no phase convoy, 320 B/lane load depth (20 float4).
__global__ __launch_bounds__(256, 2) void BL_36721970381090_kernel(
    const float* __restrict__ x,
    const float* __restrict__ W11,
    const float* __restrict__ fc2_w,
    const float* __restrict__ bias1,
    const float* __restrict__ W12,
    const float* __restrict__ fc4_w,
    const float* __restrict__ bias2,
    float* __restrict__ out)
{
    __shared__ __align__(16) unsigned short W11L[128 * 64];  // 16384 B, swizzled
    __shared__ __align__(16) float biasT[NT1 * 128];         //  2560 B  [u][t]
    __shared__ __align__(16) float w12L[NO0 * 128];          //  1536 B  [o][t]
    __shared__ float b2L[4];

    const int tid = threadIdx.x;
    const int w   = tid >> 6;   // wave 0..3
    const int l   = tid & 63;
    const int lr  = l & 15;     // batch slot / A row
    const int lg  = l >> 4;     // k-group (8 d per group)

    // ---------------- prologue: stage constants -> LDS --------------------
    {
        unsigned* WL = (unsigned*)W11L;
        for (int i = tid; i < 128 * 32; i += 256) {
            const int t = i >> 5, j = i & 31;       // dword j = d-pair (2j,2j+1)
            unsigned pk = 0u;
            if (t < NT0 && j < 20) {
                const float f0 = W11[t * ND1 + 2 * j];
                const float f1 = W11[t * ND1 + 2 * j + 1];
                asm("v_cvt_pk_bf16_f32 %0, %1, %2" : "=v"(pk) : "v"(f0), "v"(f1));
            }
            WL[t * 32 + (j ^ ((t & 7) << 2))] = pk; // XOR bank swizzle
        }
        for (int i = tid; i < NT1 * 128; i += 256) {
            const int u = i >> 7, t = i & 127;
            biasT[i] = (t < NT0) ? bias1[t * NT1 + u] : 0.f;
        }
        for (int i = tid; i < NO0 * 128; i += 256) {
            const int o = i >> 7, t = i & 127;
            w12L[i] = (t < NT0) ? W12[o * NT0 + t] : 0.f;
        }
        if (tid < NO0) b2L[tid] = bias2[tid];
    }

    float fc4r[NT1];
#pragma unroll
    for (int u = 0; u < NT1; ++u) fc4r[u] = fc4_w[u];

    __syncthreads();   // the ONLY barrier — waves independent from here

    // ---------------- phase 1: x -> in-register B-fragments ----------------
    const int bbase = (blockIdx.x * 4 + w) * 16;   // this wave's 16 batches

    unsigned b0[NT1][4];                           // B-frag kk=0 (d 0..32)
    unsigned b1[NT1][4];                           // B-frag kk=1 (d 32..40, lg0)
#pragma unroll
    for (int u = 0; u < NT1; ++u)
#pragma unroll
        for (int j = 0; j < 4; ++j) b1[u][j] = 0u;

    {
        // chunk A: batch lr, d = lg*8 .. lg*8+8  (80 floats, 20 float4)
        const float4* xa = (const float4*)(x + (size_t)(bbase + lr) * 400 + lg * 80);
        float4 xq[20];
#pragma unroll
        for (int i = 0; i < 20; ++i) xq[i] = xa[i];
#pragma unroll
        for (int j = 0; j < 4; ++j) {              // d-pair (2j, 2j+1) in chunk
            const float* xv = (const float*)&xq[j * 5];
#pragma unroll
            for (int u = 0; u < NT1; ++u) {
                float a0 = 0.f, a1 = 0.f;
#pragma unroll
                for (int s = 0; s < ND2; ++s) {
                    const float fw = fc2_w[u * ND2 + s];    // uniform: s_load
                    a0 = fmaf(xv[s], fw, a0);
                    a1 = fmaf(xv[10 + s], fw, a1);
                }
                asm("v_cvt_pk_bf16_f32 %0, %1, %2" : "=v"(b0[u][j]) : "v"(a0), "v"(a1));
            }
        }

        // chunk B (lg==0 lanes only): d = 32..40, two half-loads
        if (lg == 0) {
            const float4* xc = (const float4*)(x + (size_t)(bbase + lr) * 400 + 320);
#pragma unroll
            for (int h = 0; h < 2; ++h) {
                float4 xh[10];
#pragma unroll
                for (int i = 0; i < 10; ++i) xh[i] = xc[h * 10 + i];
#pragma unroll
                for (int j = 0; j < 2; ++j) {      // pairs (32+2(2h+j), +1)
                    const float* xv = (const float*)&xh[j * 5];
#pragma unroll
                    for (int u = 0; u < NT1; ++u) {
                        float a0 = 0.f, a1 = 0.f;
#pragma unroll
                        for (int s = 0; s < ND2; ++s) {
                            const float fw = fc2_w[u * ND2 + s];
                            a0 = fmaf(xv[s], fw, a0);
                            a1 = fmaf(xv[10 + s], fw, a1);
                        }
                        asm("v_cvt_pk_bf16_f32 %0, %1, %2"
                            : "=v"(b1[u][2 * h + j]) : "v"(a0), "v"(a1));
                    }
                }
            }
        }
    }

    // ---------------- phase 2: MFMA over all 128 t-rows --------------------
    float st[8][4];
#pragma unroll
    for (int mt = 0; mt < 8; ++mt)
#pragma unroll
        for (int r = 0; r < 4; ++r) st[mt][r] = 0.f;

    const char* WLb = (const char*)W11L;
#pragma unroll
    for (int mt = 0; mt < 8; ++mt) {
        const int t = mt * 16 + lr;
        const int sw = (t & 7) << 4;               // byte swizzle
        const short8 a0 = *(const short8*)(WLb + ((t * 128 + lg * 16) ^ sw));
        const short8 a1 = *(const short8*)(WLb + ((t * 128 + 64 + lg * 16) ^ sw));
#pragma unroll
        for (int u = 0; u < NT1; ++u) {
            const short8 bf0 = *(const short8*)&b0[u][0];
            const short8 bf1 = *(const short8*)&b1[u][0];
            f32x4 z = {0.f, 0.f, 0.f, 0.f};
            z = __builtin_amdgcn_mfma_f32_16x16x32_bf16(a1, bf1, z, 0, 0, 0);
            z = __builtin_amdgcn_mfma_f32_16x16x32_bf16(a0, bf0, z, 0, 0, 0);
            const float4 bv = *(const float4*)&biasT[u * 128 + mt * 16 + lg * 4];
            const float* bvp = (const float*)&bv;
#pragma unroll
            for (int r = 0; r < 4; ++r)
                st[mt][r] += fc4r[u] * fmaxf(z[r] + bvp[r], 0.f);
        }
    }

    // ---------------- epilogue: in-lane t-reduce + 2 shfls -----------------
    float po[NO0];
#pragma unroll
    for (int o = 0; o < NO0; ++o) {
        float a = 0.f;
#pragma unroll
        for (int mt = 0; mt < 8; ++mt) {
            const float4 wv = *(const float4*)&w12L[o * 128 + mt * 16 + lg * 4];
            const float* wvp = (const float*)&wv;
#pragma unroll
            for (int r = 0; r < 4; ++r)
                a = fmaf(wvp[r], st[mt][r], a);
        }
        a += __shfl_xor(a, 16, 64);                // reduce over lg groups
        a += __shfl_xor(a, 32, 64);
        po[o] = a;
    }
    if (l < 16) {
#pragma unroll
        for (int o = 0; o < NO0; ++o)
            out[(size_t)(bbase + l) * NO0 + o] = po[o] + b2L[o];
    }
}

extern "C" void kernel_launch(void* const* d_in, const int* in_sizes, int n_in,
                              void* d_out, int out_size, void* d_ws, size_t ws_size,
                              hipStream_t stream) {
    const float* x      = (const float*)d_in[0];
    const float* W11    = (const float*)d_in[1];
    const float* fc2_w  = (const float*)d_in[2];
    const float* bias1  = (const float*)d_in[3];
    const float* W12    = (const float*)d_in[4];
    const float* fc4_w  = (const float*)d_in[5];
    const float* bias2  = (const float*)d_in[6];
    float* out = (float*)d_out;

    const int blocks = NB / 64;   // 2048 blocks x 4 waves x 16 batches
    BL_36721970381090_kernel<<<blocks, 256, 0, stream>>>(
        x, W11, fc2_w, bias1, W12, fc4_w, bias2, out);
}

// Round 26
// 44.277 us; speedup vs baseline: 1.3138x; 1.2686x over previous
//
#include <hip/hip_runtime.h>

// Problem sizes
#define NB  131072
#define ND1 40
#define ND2 10
#define NT0 120
#define NT1 5
#define NO0 3

#define NBW 32                  // batches per workgroup
#define XTILE (NBW * ND1 * ND2) // 12800 floats
#define PK  40                  // Ybf row pitch (bf16 elems)

typedef __attribute__((ext_vector_type(8))) short  short8;
typedef __attribute__((ext_vector_type(4))) float  f32x4;

// R22 (best measured: 44.1 us = 76% of stream ceiling).
//  phase 1: load-all (12.5 float4/thread in flight, coalesced 80B units) ->
//           fp32 FMA -> v_cvt_pk_bf16_f32 -> Ybf[u][b][d] in LDS.
//  phase 2: MFMA bf16: Z[t,b]=sum_d W11[t,d]*Y_u[d,b];
//           st += fc4[u]*relu(Z+bias1).  (t padded to 128, d to 64.)
//  epilogue: out[o,b] = sum_t W12[o,t]*st[t,b].
// Structural probes all null/regressed: staging(R15/17), vmcnt pipeline(R16),
// reg prefetch(R21), balance(R23), small blocks(R13/24), zero-barrier(R25).
__global__ __launch_bounds__(256, 2) void BL_36721970381090_kernel(
    const float* __restrict__ x,
    const float* __restrict__ W11,
    const float* __restrict__ fc2_w,
    const float* __restrict__ bias1,
    const float* __restrict__ W12,
    const float* __restrict__ fc4_w,
    const float* __restrict__ bias2,
    float* __restrict__ out)
{
    __shared__ __align__(16) unsigned short Ybf[NT1 * NBW * PK]; // 12800 B
    __shared__ float biasL[128 * NT1];                           //  2560 B
    __shared__ float w12L[NO0 * 128];                            //  1536 B
    __shared__ float b2L[4];
    __shared__ float redL[4 * NO0 * NBW];                        //  1536 B

    const int tid = threadIdx.x;
    const int wg  = blockIdx.x;
    const int w   = tid >> 6;   // wave 0..3
    const int l   = tid & 63;
    const int lr  = l & 15;     // A row / B col within 16-tile
    const int lg  = l >> 4;     // k-group

    // ---------------- prologue: constants -> LDS --------------------------
    for (int i = tid; i < 128 * NT1; i += 256)
        biasL[i] = (i < NT0 * NT1) ? bias1[i] : 0.f;
    for (int i = tid; i < NO0 * 128; i += 256) {
        const int o = i >> 7, t = i & 127;
        w12L[i] = (t < NT0) ? W12[o * NT0 + t] : 0.f;
    }
    if (tid < NO0) b2L[tid] = bias2[tid];

    float fc4r[NT1];
#pragma unroll
    for (int u = 0; u < NT1; ++u) fc4r[u] = fc4_w[u];

    // A-fragments: W11 -> bf16, masked (t<120, d<40)
    short8 afr[2][2];
#pragma unroll
    for (int mt = 0; mt < 2; ++mt) {
        const int t  = w * 32 + mt * 16 + lr;
        const int tc = t < NT0 ? t : NT0 - 1;
#pragma unroll
        for (int kk = 0; kk < 2; ++kk) {
            const int cb = kk * 32 + lg * 8;
            const int cc = cb <= 32 ? cb : 0;
            const float4* pw = (const float4*)(W11 + tc * ND1 + cc);
            const float4 w0 = pw[0], w1 = pw[1];
            const bool v = (t < NT0) && (cb <= 32);
            unsigned p01, p23, p45, p67;
            asm("v_cvt_pk_bf16_f32 %0, %1, %2" : "=v"(p01) : "v"(w0.x), "v"(w0.y));
            asm("v_cvt_pk_bf16_f32 %0, %1, %2" : "=v"(p23) : "v"(w0.z), "v"(w0.w));
            asm("v_cvt_pk_bf16_f32 %0, %1, %2" : "=v"(p45) : "v"(w1.x), "v"(w1.y));
            asm("v_cvt_pk_bf16_f32 %0, %1, %2" : "=v"(p67) : "v"(w1.z), "v"(w1.w));
            short8 f;
            f[0] = v ? (short)(p01 & 0xFFFF) : (short)0;
            f[1] = v ? (short)(p01 >> 16)    : (short)0;
            f[2] = v ? (short)(p23 & 0xFFFF) : (short)0;
            f[3] = v ? (short)(p23 >> 16)    : (short)0;
            f[4] = v ? (short)(p45 & 0xFFFF) : (short)0;
            f[5] = v ? (short)(p45 >> 16)    : (short)0;
            f[6] = v ? (short)(p67 & 0xFFFF) : (short)0;
            f[7] = v ? (short)(p67 >> 16)    : (short)0;
            afr[mt][kk] = f;
        }
    }

    // ---------------- phase 1: load-all, then compute ---------------------
    {
        const float* gx = x + (size_t)wg * XTILE;
        unsigned* Yw = (unsigned*)Ybf;
        const bool act2 = (tid < 128);

        float4 xq0[5], xq1[5], xq2[5];
        const float4* xr0 = (const float4*)(gx + (0 * 256 + tid) * 20);
        const float4* xr1 = (const float4*)(gx + (1 * 256 + tid) * 20);
        const float4* xr2 = (const float4*)(gx + (2 * 256 + tid) * 20);
#pragma unroll
        for (int i = 0; i < 5; ++i) xq0[i] = xr0[i];
#pragma unroll
        for (int i = 0; i < 5; ++i) xq1[i] = xr1[i];
        if (act2) {
#pragma unroll
            for (int i = 0; i < 5; ++i) xq2[i] = xr2[i];
        }

        const float4* bufs[3] = {xq0, xq1, xq2};
#pragma unroll
        for (int rep = 0; rep < 3; ++rep) {
            if (rep < 2 || act2) {
                const int q = rep * 256 + tid;
                const int batch = q / 20;
                const int pair  = q - batch * 20;
                const float* xv = (const float*)bufs[rep];
#pragma unroll
                for (int u = 0; u < NT1; ++u) {
                    float a0 = 0.f, a1 = 0.f;
#pragma unroll
                    for (int s = 0; s < ND2; ++s) {
                        const float fw = fc2_w[u * ND2 + s];   // uniform: s_load
                        a0 = fmaf(xv[s], fw, a0);
                        a1 = fmaf(xv[10 + s], fw, a1);
                    }
                    unsigned pk;
                    asm("v_cvt_pk_bf16_f32 %0, %1, %2" : "=v"(pk) : "v"(a0), "v"(a1));
                    Yw[u * (NBW * PK / 2) + batch * (PK / 2) + pair] = pk;
                }
            }
        }
    }
    __syncthreads();   // Ybf + constants visible

    // ---------------- phase 2: MFMA + fused relu/fc4 ----------------------
    float st[2][2][4];          // [m-tile][n-tile][reg]
#pragma unroll
    for (int mt = 0; mt < 2; ++mt)
#pragma unroll
        for (int nt = 0; nt < 2; ++nt)
#pragma unroll
            for (int r = 0; r < 4; ++r) st[mt][nt][r] = 0.f;

    const short8 zf = {0, 0, 0, 0, 0, 0, 0, 0};
#pragma unroll
    for (int u = 0; u < NT1; ++u) {
        float bv[2][4];
#pragma unroll
        for (int mt = 0; mt < 2; ++mt)
#pragma unroll
            for (int r = 0; r < 4; ++r)
                bv[mt][r] = biasL[(w * 32 + mt * 16 + lg * 4 + r) * NT1 + u];
        const unsigned short* Yu = &Ybf[u * (NBW * PK)];
#pragma unroll
        for (int nt = 0; nt < 2; ++nt) {
            const short8 b0 = *(const short8*)&Yu[(nt * 16 + lr) * PK + lg * 8];
            short8 b1 = zf;
            if (lg == 0) b1 = *(const short8*)&Yu[(nt * 16 + lr) * PK + 32];
#pragma unroll
            for (int mt = 0; mt < 2; ++mt) {
                f32x4 z = {0.f, 0.f, 0.f, 0.f};
                z = __builtin_amdgcn_mfma_f32_16x16x32_bf16(afr[mt][0], b0, z, 0, 0, 0);
                z = __builtin_amdgcn_mfma_f32_16x16x32_bf16(afr[mt][1], b1, z, 0, 0, 0);
#pragma unroll
                for (int r = 0; r < 4; ++r)
                    st[mt][nt][r] += fc4r[u] * fmaxf(z[r] + bv[mt][r], 0.f);
            }
        }
    }

    // ---------------- epilogue: out[o,b] = sum_t W12[o,t]*st --------------
    float po[2][NO0];
#pragma unroll
    for (int nt = 0; nt < 2; ++nt)
#pragma unroll
        for (int o = 0; o < NO0; ++o) {
            float a = 0.f;
#pragma unroll
            for (int mt = 0; mt < 2; ++mt)
#pragma unroll
                for (int r = 0; r < 4; ++r)
                    a = fmaf(w12L[o * 128 + (w * 32 + mt * 16 + lg * 4 + r)],
                             st[mt][nt][r], a);
            a += __shfl_xor(a, 16, 64);
            a += __shfl_xor(a, 32, 64);
            po[nt][o] = a;
        }
    if (l < 16) {
#pragma unroll
        for (int nt = 0; nt < 2; ++nt)
#pragma unroll
            for (int o = 0; o < NO0; ++o)
                redL[(w * NO0 + o) * NBW + nt * 16 + l] = po[nt][o];
    }
    __syncthreads();

    if (tid < NO0 * NBW) {                    // 96 threads
        const int o  = tid >> 5;
        const int bc = tid & 31;
        const float s = redL[(0 * NO0 + o) * NBW + bc]
                      + redL[(1 * NO0 + o) * NBW + bc]
                      + redL[(2 * NO0 + o) * NBW + bc]
                      + redL[(3 * NO0 + o) * NBW + bc]
                      + b2L[o];
        out[((size_t)wg * NBW + bc) * NO0 + o] = s;
    }
}

extern "C" void kernel_launch(void* const* d_in, const int* in_sizes, int n_in,
                              void* d_out, int out_size, void* d_ws, size_t ws_size,
                              hipStream_t stream) {
    const float* x      = (const float*)d_in[0];
    const float* W11    = (const float*)d_in[1];
    const float* fc2_w  = (const float*)d_in[2];
    const float* bias1  = (const float*)d_in[3];
    const float* W12    = (const float*)d_in[4];
    const float* fc4_w  = (const float*)d_in[5];
    const float* bias2  = (const float*)d_in[6];
    float* out = (float*)d_out;

    const int blocks = NB / NBW;   // 4096
    BL_36721970381090_kernel<<<blocks, 256, 0, stream>>>(
        x, W11, fc2_w, bias1, W12, fc4_w, bias2, out);
}